// Round 5
// baseline (319.008 us; speedup 1.0000x reference)
//
#include <hip/hip_runtime.h>
#include <hip/hip_bf16.h>

// Problem constants (fixed by the reference)
#define BB 4
#define TT 1024
#define DD 1024
#define HH 16
#define HDIM 64
#define MM (BB*TT)          // 4096

typedef unsigned short u16;
typedef __attribute__((ext_vector_type(8))) short bf16x8;   // 8 bf16 = 4 VGPRs
typedef __attribute__((ext_vector_type(4))) float f32x4;
typedef __attribute__((ext_vector_type(4))) unsigned short u16x4;

__device__ __forceinline__ u16 f2bf(float f) {
    union { float f; unsigned u; } v; v.f = f;
    return (u16)((v.u + 0x7fffu + ((v.u >> 16) & 1u)) >> 16);   // RNE
}
__device__ __forceinline__ float bf2f(u16 h) {
    union { unsigned u; float f; } v; v.u = ((unsigned)h) << 16; return v.f;
}

// async global->LDS, 16B per lane; lds dest = wave-uniform base + lane*16
__device__ __forceinline__ void gload16(const void* g, void* l) {
    __builtin_amdgcn_global_load_lds(
        (const __attribute__((address_space(1))) unsigned int*)g,
        (__attribute__((address_space(3))) unsigned int*)l, 16, 0, 0);
}

// src f32 -> hi = bf16(src), lo = bf16(src - hi)   (lo may be null)
__global__ __launch_bounds__(256)
void split_kernel(const float* __restrict__ src, u16* __restrict__ hi,
                  u16* __restrict__ lo)
{
    const size_t i = ((size_t)blockIdx.x * 256 + threadIdx.x) * 4;
    const float4 v = *(const float4*)&src[i];
    u16x4 h;
    h[0] = f2bf(v.x); h[1] = f2bf(v.y); h[2] = f2bf(v.z); h[3] = f2bf(v.w);
    *(u16x4*)&hi[i] = h;
    if (lo != nullptr) {
        u16x4 l;
        l[0] = f2bf(v.x - bf2f(h[0]));
        l[1] = f2bf(v.y - bf2f(h[1]));
        l[2] = f2bf(v.z - bf2f(h[2]));
        l[3] = f2bf(v.w - bf2f(h[3]));
        *(u16x4*)&lo[i] = l;
    }
}

// k16 [b][h][t][64] -> k16T [b][h][d][1024]   (per-head 64-col transpose)
__global__ __launch_bounds__(256)
void ktrans_kernel(const u16* __restrict__ k16, u16* __restrict__ k16T)
{
    __shared__ u16 tmp[64][72];
    const int tc = blockIdx.x, h = blockIdx.y, b = blockIdx.z;
    const size_t hb = ((size_t)(b * HH + h)) << 16;
    const int tid = threadIdx.x;
    const int sr = tid >> 2, sc = (tid & 3) * 8;
    *(bf16x8*)&tmp[sr][sc]      = *(const bf16x8*)&k16[hb + (size_t)(tc * 64 + sr) * HDIM + sc];
    *(bf16x8*)&tmp[sr][sc + 32] = *(const bf16x8*)&k16[hb + (size_t)(tc * 64 + sr) * HDIM + sc + 32];
    __syncthreads();
#pragma unroll
    for (int half = 0; half < 2; ++half) {
        bf16x8 v;
#pragma unroll
        for (int j = 0; j < 8; ++j) v[j] = (short)tmp[sc + half * 32 + j][sr];
        *(bf16x8*)&k16T[hb + (size_t)sr * TT + tc * 64 + sc + half * 32] = v;
    }
}

// ---------------------------------------------------------------------------
// MFMA GEMM: C = A @ B^T + bias (unchanged from round 3).
// ---------------------------------------------------------------------------
template<bool SPLIT, int MODE>
__global__ __launch_bounds__(256)
void gemm_mfma(const u16* __restrict__ Ah, const u16* __restrict__ Al,
               const u16* __restrict__ Bh, const u16* __restrict__ Bl,
               const float* __restrict__ bias,
               float* __restrict__ dstF, u16* __restrict__ dstH1,
               u16* __restrict__ dstH2, const float* __restrict__ kaux,
               const int M, const int N, const int K)
{
    __shared__ u16 As[128][64];
    __shared__ u16 Bs[128][64];
    __shared__ u16 As2[SPLIT ? 128 : 1][64];
    __shared__ u16 Bs2[SPLIT ? 128 : 1][64];

    const int tid  = threadIdx.x;
    const int w    = tid >> 6;
    const int lane = tid & 63;
    const int lg   = lane >> 4;
    const int lr   = lane & 15;
    const int wr   = w >> 1, wc = w & 1;
    const int m0   = blockIdx.y * 128, n0 = blockIdx.x * 128;

    const f32x4 zero = {0.f, 0.f, 0.f, 0.f};
    f32x4 acc[4][4];
#pragma unroll
    for (int i = 0; i < 4; ++i)
#pragma unroll
        for (int j = 0; j < 4; ++j) acc[i][j] = zero;

    const int srow = tid >> 3;
    const int scol = (tid & 7) * 8;
    const int ldr  = w << 3;

    for (int k0 = 0; k0 < K; k0 += 64) {
        __syncthreads();
#pragma unroll
        for (int i = 0; i < 4; ++i) {
            const size_t ga = (size_t)(m0 + i * 32 + srow) * K + k0 + scol;
            const size_t gb = (size_t)(n0 + i * 32 + srow) * K + k0 + scol;
            gload16(&Ah[ga], &As[i * 32 + ldr][0]);
            gload16(&Bh[gb], &Bs[i * 32 + ldr][0]);
            if constexpr (SPLIT) {
                gload16(&Al[ga], &As2[i * 32 + ldr][0]);
                gload16(&Bl[gb], &Bs2[i * 32 + ldr][0]);
            }
        }
        __syncthreads();
#pragma unroll
        for (int kk = 0; kk < 2; ++kk) {
            const int koff = kk * 32 + lg * 8;
            bf16x8 a_h[4], b_h[4];
#pragma unroll
            for (int f = 0; f < 4; ++f) {
                a_h[f] = *(const bf16x8*)&As[wr * 64 + f * 16 + lr][koff];
                b_h[f] = *(const bf16x8*)&Bs[wc * 64 + f * 16 + lr][koff];
            }
            if constexpr (SPLIT) {
                bf16x8 a_l[4], b_l[4];
#pragma unroll
                for (int f = 0; f < 4; ++f) {
                    a_l[f] = *(const bf16x8*)&As2[wr * 64 + f * 16 + lr][koff];
                    b_l[f] = *(const bf16x8*)&Bs2[wc * 64 + f * 16 + lr][koff];
                }
#pragma unroll
                for (int mf = 0; mf < 4; ++mf)
#pragma unroll
                    for (int nf = 0; nf < 4; ++nf) {
                        acc[mf][nf] = __builtin_amdgcn_mfma_f32_16x16x32_bf16(a_h[mf], b_h[nf], acc[mf][nf], 0, 0, 0);
                        acc[mf][nf] = __builtin_amdgcn_mfma_f32_16x16x32_bf16(a_l[mf], b_h[nf], acc[mf][nf], 0, 0, 0);
                        acc[mf][nf] = __builtin_amdgcn_mfma_f32_16x16x32_bf16(a_h[mf], b_l[nf], acc[mf][nf], 0, 0, 0);
                    }
            } else {
#pragma unroll
                for (int mf = 0; mf < 4; ++mf)
#pragma unroll
                    for (int nf = 0; nf < 4; ++nf)
                        acc[mf][nf] = __builtin_amdgcn_mfma_f32_16x16x32_bf16(a_h[mf], b_h[nf], acc[mf][nf], 0, 0, 0);
            }
        }
    }

#pragma unroll
    for (int mf = 0; mf < 4; ++mf)
#pragma unroll
        for (int nf = 0; nf < 4; ++nf)
#pragma unroll
            for (int j = 0; j < 4; ++j) {
                const int gm = m0 + wr * 64 + mf * 16 + lg * 4 + j;
                const int gn = n0 + wc * 64 + nf * 16 + lr;
                const float v = acc[mf][nf][j] + bias[gn];
                if constexpr (MODE == 0) {
                    const int bb = gm >> 10, t = gm & 1023;
                    const int c = gn >> 10, hh = (gn & 1023) >> 6, d = gn & 63;
                    const size_t idx = ((((size_t)bb * HH + hh) << 10) + t) * HDIM + d;
                    if (c == 0) dstH1[idx] = f2bf(v * 0.125f);
                    else { dstF[idx] = v; dstH2[idx] = f2bf(v); }
                } else if constexpr (MODE == 1) {
                    const int bb = gm >> 10, t = gm & 1023;
                    const int hh = gn >> 6, d = gn & 63;
                    const size_t idx = ((((size_t)bb * HH + hh) << 10) + t) * HDIM + d;
                    dstH1[idx] = f2bf(v + kaux[idx]);
                } else {
                    dstF[(size_t)gm * N + gn] = v;
                }
            }
}

// ---------------------------------------------------------------------------
// Fused attention, single-exp. Block = 16 q-rows of one (b,h), 4 waves.
// Sweep 1: S=QK^T, P=exp(S) stored f32 in LDS (16x1024), rowsums.
// Sweep 2: attn = P*ri (f32 nontemporal), PV unnormalized (P->bf16 on the
//          fly), ctx = acc*ri -> bf16.
// A/B frag k-map: k = 8*(lane>>4)+i; C/D map: col=lane&15, row=4*(lane>>4)+reg.
// ---------------------------------------------------------------------------
__global__ __launch_bounds__(256)
void attn_fused(const u16* __restrict__ qg, const u16* __restrict__ kTg,
                const u16* __restrict__ kpg,
                float* __restrict__ attn, u16* __restrict__ ch)
{
    __shared__ float P_s[16][1028];     // unnormalized exp(S), f32
    __shared__ u16 kv_s[64][72];        // kp tile (sweep1) / kT tile (sweep2)
    __shared__ float rowsum_s[4][16];

    const int tid  = threadIdx.x;
    const int w    = tid >> 6;          // wave 0..3
    const int lane = tid & 63;
    const int lg   = lane >> 4;         // 0..3
    const int lr   = lane & 15;         // 0..15
    const int q0   = blockIdx.x * 16;
    const int h = blockIdx.y, b = blockIdx.z;
    const size_t hb = ((size_t)(b * HH + h)) << 16;   // head base (T*64)

    // Q fragments: A row = lr (q row), k = 32*kk + lg*8 + i
    bf16x8 qf0, qf1;
    {
        const size_t base = hb + (size_t)(q0 + lr) * HDIM + lg * 8;
        qf0 = *(const bf16x8*)&qg[base];
        qf1 = *(const bf16x8*)&qg[base + 32];
    }

    const int sr = tid >> 2;            // staging row 0..63
    const int sc = (tid & 3) * 8;       // staging col chunk

    // ---- sweep 1: QK^T + exp + rowsum ----
    float rs[4] = {0.f, 0.f, 0.f, 0.f};
    for (int t = 0; t < TT / 64; ++t) {
        __syncthreads();
        *(bf16x8*)&kv_s[sr][sc]      = *(const bf16x8*)&kpg[hb + (size_t)(t * 64 + sr) * HDIM + sc];
        *(bf16x8*)&kv_s[sr][sc + 32] = *(const bf16x8*)&kpg[hb + (size_t)(t * 64 + sr) * HDIM + sc + 32];
        __syncthreads();
        // wave w handles kv 16-chunk w of this 64-tile
        f32x4 acc = {0.f, 0.f, 0.f, 0.f};
        const bf16x8 b0 = *(const bf16x8*)&kv_s[w * 16 + lr][lg * 8];
        const bf16x8 b1 = *(const bf16x8*)&kv_s[w * 16 + lr][lg * 8 + 32];
        acc = __builtin_amdgcn_mfma_f32_16x16x32_bf16(qf0, b0, acc, 0, 0, 0);
        acc = __builtin_amdgcn_mfma_f32_16x16x32_bf16(qf1, b1, acc, 0, 0, 0);
        const int col = t * 64 + w * 16 + lr;
#pragma unroll
        for (int j = 0; j < 4; ++j) {
            const float p = __expf(acc[j]);
            P_s[lg * 4 + j][col] = p;
            rs[j] += p;
        }
    }
    // reduce rowsums over the 16 kv-col lanes (lr)
#pragma unroll
    for (int off = 1; off < 16; off <<= 1)
#pragma unroll
        for (int j = 0; j < 4; ++j) rs[j] += __shfl_xor(rs[j], off);
    if (lr == 0) {
#pragma unroll
        for (int j = 0; j < 4; ++j) rowsum_s[w][lg * 4 + j] = rs[j];
    }
    __syncthreads();

    // per-thread normalizers
    const int arow = tid >> 4;                      // attn-write row
    const float ri_w = 1.f / (rowsum_s[0][arow] + rowsum_s[1][arow] +
                              rowsum_s[2][arow] + rowsum_s[3][arow]);
    float ri_c[4];
#pragma unroll
    for (int j = 0; j < 4; ++j) {
        const int r = lg * 4 + j;
        ri_c[j] = 1.f / (rowsum_s[0][r] + rowsum_s[1][r] +
                         rowsum_s[2][r] + rowsum_s[3][r]);
    }

    // ---- sweep 2: attn write + PV ----
    const size_t abase = ((((size_t)b * HH + h) << 10) + q0) << 10;
    const int ac4 = (tid & 15) * 4;                 // attn-write col group
    f32x4 cacc = {0.f, 0.f, 0.f, 0.f};

    for (int t = 0; t < TT / 64; ++t) {
        __syncthreads();
        *(bf16x8*)&kv_s[sr][sc]      = *(const bf16x8*)&kTg[hb + (size_t)sr * TT + t * 64 + sc];
        *(bf16x8*)&kv_s[sr][sc + 32] = *(const bf16x8*)&kTg[hb + (size_t)sr * TT + t * 64 + sc + 32];
        __syncthreads();

        // attn write: 4 f32 per thread, nontemporal (don't pollute L2)
        {
            const int col = t * 64 + ac4;
            const f32x4 pv = *(const f32x4*)&P_s[arow][col];
            f32x4 o = pv * ri_w;
            __builtin_nontemporal_store(o, (f32x4*)&attn[abase + (size_t)arow * TT + col]);
        }

        // PV: A = P rows (lr), k = kv; B = kT rows (d = w*16+lr)
        bf16x8 pa0, pa1;
#pragma unroll
        for (int i = 0; i < 8; ++i) {
            pa0[i] = (short)f2bf(P_s[lr][t * 64 + lg * 8 + i]);
            pa1[i] = (short)f2bf(P_s[lr][t * 64 + 32 + lg * 8 + i]);
        }
        const bf16x8 kb0 = *(const bf16x8*)&kv_s[w * 16 + lr][lg * 8];
        const bf16x8 kb1 = *(const bf16x8*)&kv_s[w * 16 + lr][lg * 8 + 32];
        cacc = __builtin_amdgcn_mfma_f32_16x16x32_bf16(pa0, kb0, cacc, 0, 0, 0);
        cacc = __builtin_amdgcn_mfma_f32_16x16x32_bf16(pa1, kb1, cacc, 0, 0, 0);
    }

    // ctx -> bf16 [B][T][H*64]; wave w owns d-chunk w
#pragma unroll
    for (int j = 0; j < 4; ++j) {
        const int qr = q0 + lg * 4 + j;
        ch[(((size_t)b << 10) + qr) * DD + h * HDIM + w * 16 + lr] =
            f2bf(cacc[j] * ri_c[j]);
    }
}

extern "C" void kernel_launch(void* const* d_in, const int* in_sizes, int n_in,
                              void* d_out, int out_size, void* d_ws, size_t ws_size,
                              hipStream_t stream)
{
    const float* x  = (const float*)d_in[0];
    const float* pe = (const float*)d_in[1];
    const float* Wc = (const float*)d_in[2];
    const float* bc = (const float*)d_in[3];
    const float* Wp = (const float*)d_in[4];
    const float* bp = (const float*)d_in[5];
    const float* Wo = (const float*)d_in[6];
    const float* bo = (const float*)d_in[7];

    float* out  = (float*)d_out;                         // [B][T][D]
    float* attn = out + (size_t)MM * DD;                 // [B][H][T][T]

    // 64 MB workspace layout (in-order stream => safe region reuse)
    char* ws = (char*)d_ws;
    float* kf32 = (float*)(ws);                          // [0,16M)   k fp32
    u16* q16  = (u16*)(ws + ((size_t)16 << 20));         // [16,24M)
    u16* k16  = (u16*)(ws + ((size_t)24 << 20));         // [24,32M)
    u16* kp16 = (u16*)(ws + ((size_t)32 << 20));         // [32,40M)
    u16* k16T = (u16*)(ws + ((size_t)56 << 20));         // [56,64M)  k transposed (after Wc split dead)
    // scratch region, phase-reused:
    u16* xh  = (u16*)(ws + ((size_t)40 << 20));          // 8MB
    u16* xl  = (u16*)(ws + ((size_t)48 << 20));          // 8MB
    u16* Wch = (u16*)(ws + ((size_t)56 << 20));          // 4MB (k16T area, consumed before ktrans)
    u16* Wcl = (u16*)(ws + ((size_t)60 << 20));          // 4MB
    u16* peh = xh, *pel = xl;                            // after cqk
    u16* Wph = (u16*)(ws + ((size_t)32 << 20));          // pre-kp16 writes? NO -- kp16 written by same gemm.
    u16* Wpl = (u16*)(ws + ((size_t)34 << 20));
    u16* chh = xh;                                       // ctx bf16, after pk
    u16* Woh = (u16*)(ws + ((size_t)48 << 20));          // 2MB (xl dead)

    // NOTE on Wp: kp16 region is [32,40M) and gemm<true,1> writes kp16 while
    // reading Wph/Wpl -- they must not alias. Put Wp split at [36,40M)?
    // Still inside kp16 (8MB = 4M u16). kp16 uses [32,40M) fully.
    // Safe spot: [24,32M) is k16 (still needed by ktrans? no -- ktrans runs
    // before pk-gemm; k16 needed only by ktrans). k16 dead after ktrans =>
    // Wp split can live in... k16 is NOT dead: attn uses k16T only. OK:
    // place Wp split in the first 4MB of kf32? kf32 needed by pk-gemm (kaux).
    // Use [60,64M): Wcl dead after cqk-gemm; k16T occupies [56,64M) ONLY
    // after ktrans... ktrans writes all of [56,64M). Conflict.
    // Final: shrink k16T to [56,64M) and put Wp split in x's hi region tail:
    // peh/pel occupy [40,48M)+[48,56M) fully (4M u16 each = 8MB each).
    // Remaining truly-free region during pk-gemm: none of the above.
    // Solution: kf32 occupies [0,16M); k fp32 is 4M floats = 16MB exactly.
    // pk-gemm reads kaux=kf32 and writes kp16 -- distinct. Wp split (4MB)
    // goes into... q16 region [16,24M)? q16 needed later by attn. k16
    // [24,32M) IS dead after ktrans (attn reads k16T). ktrans runs before
    // split(Wp). => Wph=[24,26M), Wpl=[26,28M). Correct and non-aliasing.
    Wph = (u16*)(ws + ((size_t)24 << 20));
    Wpl = (u16*)(ws + ((size_t)26 << 20));

    // 1) splits for cqk
    split_kernel<<<4096, 256, 0, stream>>>(x, xh, xl);
    split_kernel<<<2048, 256, 0, stream>>>(Wc, Wch, Wcl);
    // 2) cqk = x @ Wc^T + bc -> q16 (scaled), kf32, k16
    gemm_mfma<true, 0><<<dim3(16, 32), 256, 0, stream>>>(
        xh, xl, Wch, Wcl, bc, kf32, q16, k16, nullptr, MM, 2048, DD);
    // 3) k16T = transpose(k16)  (overwrites Wc split -- dead after gemm)
    ktrans_kernel<<<dim3(16, HH, BB), 256, 0, stream>>>(k16, k16T);
    // 4) splits for pk (Wp split into k16's region -- k16 dead after ktrans)
    split_kernel<<<4096, 256, 0, stream>>>(pe, peh, pel);
    split_kernel<<<1024, 256, 0, stream>>>(Wp, Wph, Wpl);
    // 5) pk = pe @ Wp^T + bp; kp16 = bf16(pk + k)
    gemm_mfma<true, 1><<<dim3(8, 32), 256, 0, stream>>>(
        peh, pel, Wph, Wpl, bp, nullptr, kp16, nullptr, kf32, MM, 1024, DD);
    // 6) attention: attn f32 + ctx bf16
    attn_fused<<<dim3(TT / 16, HH, BB), 256, 0, stream>>>(
        q16, k16T, kp16, attn, chh);
    // 7) split Wo (hi only), out = ctx @ Wo^T + bo
    split_kernel<<<1024, 256, 0, stream>>>(Wo, Woh, nullptr);
    gemm_mfma<false, 2><<<dim3(8, 32), 256, 0, stream>>>(
        chh, nullptr, Woh, nullptr, bo, out, nullptr, nullptr, nullptr, MM, 1024, DD);
}

// Round 6
// 291.833 us; speedup vs baseline: 1.0931x; 1.0931x over previous
//
#include <hip/hip_runtime.h>
#include <hip/hip_bf16.h>

// Problem constants (fixed by the reference)
#define BB 4
#define TT 1024
#define DD 1024
#define HH 16
#define HDIM 64
#define MM (BB*TT)          // 4096

typedef unsigned short u16;
typedef __attribute__((ext_vector_type(8))) short bf16x8;   // 8 bf16 = 4 VGPRs
typedef __attribute__((ext_vector_type(4))) float f32x4;
typedef __attribute__((ext_vector_type(4))) unsigned short u16x4;

__device__ __forceinline__ u16 f2bf(float f) {
    union { float f; unsigned u; } v; v.f = f;
    return (u16)((v.u + 0x7fffu + ((v.u >> 16) & 1u)) >> 16);   // RNE
}
__device__ __forceinline__ float bf2f(u16 h) {
    union { unsigned u; float f; } v; v.u = ((unsigned)h) << 16; return v.f;
}

// async global->LDS, 16B per lane; lds dest = wave-uniform base + lane*16
__device__ __forceinline__ void gload16(const void* g, void* l) {
    __builtin_amdgcn_global_load_lds(
        (const __attribute__((address_space(1))) unsigned int*)g,
        (__attribute__((address_space(3))) unsigned int*)l, 16, 0, 0);
}

// src f32 -> hi = bf16(src), lo = bf16(src - hi)   (lo may be null)
__global__ __launch_bounds__(256)
void split_kernel(const float* __restrict__ src, u16* __restrict__ hi,
                  u16* __restrict__ lo)
{
    const size_t i = ((size_t)blockIdx.x * 256 + threadIdx.x) * 4;
    const float4 v = *(const float4*)&src[i];
    u16x4 h;
    h[0] = f2bf(v.x); h[1] = f2bf(v.y); h[2] = f2bf(v.z); h[3] = f2bf(v.w);
    *(u16x4*)&hi[i] = h;
    if (lo != nullptr) {
        u16x4 l;
        l[0] = f2bf(v.x - bf2f(h[0]));
        l[1] = f2bf(v.y - bf2f(h[1]));
        l[2] = f2bf(v.z - bf2f(h[2]));
        l[3] = f2bf(v.w - bf2f(h[3]));
        *(u16x4*)&lo[i] = l;
    }
}

// k16 [b][h][t][64] -> k16T [b][h][d][1024]   (per-head 64-col transpose)
__global__ __launch_bounds__(256)
void ktrans_kernel(const u16* __restrict__ k16, u16* __restrict__ k16T)
{
    __shared__ u16 tmp[64][72];
    const int tc = blockIdx.x, h = blockIdx.y, b = blockIdx.z;
    const size_t hb = ((size_t)(b * HH + h)) << 16;
    const int tid = threadIdx.x;
    const int sr = tid >> 2, sc = (tid & 3) * 8;
    *(bf16x8*)&tmp[sr][sc]      = *(const bf16x8*)&k16[hb + (size_t)(tc * 64 + sr) * HDIM + sc];
    *(bf16x8*)&tmp[sr][sc + 32] = *(const bf16x8*)&k16[hb + (size_t)(tc * 64 + sr) * HDIM + sc + 32];
    __syncthreads();
#pragma unroll
    for (int half = 0; half < 2; ++half) {
        bf16x8 v;
#pragma unroll
        for (int j = 0; j < 8; ++j) v[j] = (short)tmp[sc + half * 32 + j][sr];
        *(bf16x8*)&k16T[hb + (size_t)sr * TT + tc * 64 + sc + half * 32] = v;
    }
}

// ---------------------------------------------------------------------------
// MFMA GEMM: C = A @ B^T + bias (unchanged from round 3).
// ---------------------------------------------------------------------------
template<bool SPLIT, int MODE>
__global__ __launch_bounds__(256)
void gemm_mfma(const u16* __restrict__ Ah, const u16* __restrict__ Al,
               const u16* __restrict__ Bh, const u16* __restrict__ Bl,
               const float* __restrict__ bias,
               float* __restrict__ dstF, u16* __restrict__ dstH1,
               u16* __restrict__ dstH2, const float* __restrict__ kaux,
               const int M, const int N, const int K)
{
    __shared__ u16 As[128][64];
    __shared__ u16 Bs[128][64];
    __shared__ u16 As2[SPLIT ? 128 : 1][64];
    __shared__ u16 Bs2[SPLIT ? 128 : 1][64];

    const int tid  = threadIdx.x;
    const int w    = tid >> 6;
    const int lane = tid & 63;
    const int lg   = lane >> 4;
    const int lr   = lane & 15;
    const int wr   = w >> 1, wc = w & 1;
    const int m0   = blockIdx.y * 128, n0 = blockIdx.x * 128;

    const f32x4 zero = {0.f, 0.f, 0.f, 0.f};
    f32x4 acc[4][4];
#pragma unroll
    for (int i = 0; i < 4; ++i)
#pragma unroll
        for (int j = 0; j < 4; ++j) acc[i][j] = zero;

    const int srow = tid >> 3;
    const int scol = (tid & 7) * 8;
    const int ldr  = w << 3;

    for (int k0 = 0; k0 < K; k0 += 64) {
        __syncthreads();
#pragma unroll
        for (int i = 0; i < 4; ++i) {
            const size_t ga = (size_t)(m0 + i * 32 + srow) * K + k0 + scol;
            const size_t gb = (size_t)(n0 + i * 32 + srow) * K + k0 + scol;
            gload16(&Ah[ga], &As[i * 32 + ldr][0]);
            gload16(&Bh[gb], &Bs[i * 32 + ldr][0]);
            if constexpr (SPLIT) {
                gload16(&Al[ga], &As2[i * 32 + ldr][0]);
                gload16(&Bl[gb], &Bs2[i * 32 + ldr][0]);
            }
        }
        __syncthreads();
#pragma unroll
        for (int kk = 0; kk < 2; ++kk) {
            const int koff = kk * 32 + lg * 8;
            bf16x8 a_h[4], b_h[4];
#pragma unroll
            for (int f = 0; f < 4; ++f) {
                a_h[f] = *(const bf16x8*)&As[wr * 64 + f * 16 + lr][koff];
                b_h[f] = *(const bf16x8*)&Bs[wc * 64 + f * 16 + lr][koff];
            }
            if constexpr (SPLIT) {
                bf16x8 a_l[4], b_l[4];
#pragma unroll
                for (int f = 0; f < 4; ++f) {
                    a_l[f] = *(const bf16x8*)&As2[wr * 64 + f * 16 + lr][koff];
                    b_l[f] = *(const bf16x8*)&Bs2[wc * 64 + f * 16 + lr][koff];
                }
#pragma unroll
                for (int mf = 0; mf < 4; ++mf)
#pragma unroll
                    for (int nf = 0; nf < 4; ++nf) {
                        acc[mf][nf] = __builtin_amdgcn_mfma_f32_16x16x32_bf16(a_h[mf], b_h[nf], acc[mf][nf], 0, 0, 0);
                        acc[mf][nf] = __builtin_amdgcn_mfma_f32_16x16x32_bf16(a_l[mf], b_h[nf], acc[mf][nf], 0, 0, 0);
                        acc[mf][nf] = __builtin_amdgcn_mfma_f32_16x16x32_bf16(a_h[mf], b_l[nf], acc[mf][nf], 0, 0, 0);
                    }
            } else {
#pragma unroll
                for (int mf = 0; mf < 4; ++mf)
#pragma unroll
                    for (int nf = 0; nf < 4; ++nf)
                        acc[mf][nf] = __builtin_amdgcn_mfma_f32_16x16x32_bf16(a_h[mf], b_h[nf], acc[mf][nf], 0, 0, 0);
            }
        }
    }

#pragma unroll
    for (int mf = 0; mf < 4; ++mf)
#pragma unroll
        for (int nf = 0; nf < 4; ++nf)
#pragma unroll
            for (int j = 0; j < 4; ++j) {
                const int gm = m0 + wr * 64 + mf * 16 + lg * 4 + j;
                const int gn = n0 + wc * 64 + nf * 16 + lr;
                const float v = acc[mf][nf][j] + bias[gn];
                if constexpr (MODE == 0) {
                    const int bb = gm >> 10, t = gm & 1023;
                    const int c = gn >> 10, hh = (gn & 1023) >> 6, d = gn & 63;
                    const size_t idx = ((((size_t)bb * HH + hh) << 10) + t) * HDIM + d;
                    if (c == 0) dstH1[idx] = f2bf(v * 0.125f);
                    else { dstF[idx] = v; dstH2[idx] = f2bf(v); }
                } else if constexpr (MODE == 1) {
                    const int bb = gm >> 10, t = gm & 1023;
                    const int hh = gn >> 6, d = gn & 63;
                    const size_t idx = ((((size_t)bb * HH + hh) << 10) + t) * HDIM + d;
                    dstH1[idx] = f2bf(v + kaux[idx]);
                } else {
                    dstF[(size_t)gm * N + gn] = v;
                }
            }
}

// ---------------------------------------------------------------------------
// Fused attention v2. Block = 16 q-rows of one (b,h), 4 waves.
// Sweep 1: S=QK^T (each wave one 16-col chunk per 64-tile), P=exp(S) stored
//          as bf16 in LDS [16][1032] (stride 516 words -> conflict-optimal
//          b128 reads), rowsums in f32.
// attn-out loop: vector LDS reads -> *ri -> nontemporal f32x4 stores.
// Sweep 2: PV with A-frags read as ds_read_b128 from P_s, kT staged in LDS;
//          ctx = acc*ri -> bf16.
// A/B frag k-map: k = 8*(lane>>4)+i; C/D map: col=lane&15, row=4*(lane>>4)+reg.
// ---------------------------------------------------------------------------
__global__ __launch_bounds__(256)
void attn_fused(const u16* __restrict__ qg, const u16* __restrict__ kTg,
                const u16* __restrict__ kpg,
                float* __restrict__ attn, u16* __restrict__ ch)
{
    __shared__ u16 P_s[16][1032];       // unnormalized exp(S), bf16; 33 KB
    __shared__ u16 kv_s[64][72];        // kp tile (sweep1) / kT tile (sweep2)
    __shared__ float rowsum_s[4][16];

    const int tid  = threadIdx.x;
    const int w    = tid >> 6;          // wave 0..3
    const int lane = tid & 63;
    const int lg   = lane >> 4;         // 0..3
    const int lr   = lane & 15;         // 0..15
    const int q0   = blockIdx.x * 16;
    const int h = blockIdx.y, b = blockIdx.z;
    const size_t hb = ((size_t)(b * HH + h)) << 16;   // head base (T*64)

    // Q fragments: A row = lr (q row), k = 32*kk + lg*8 + i
    bf16x8 qf0, qf1;
    {
        const size_t base = hb + (size_t)(q0 + lr) * HDIM + lg * 8;
        qf0 = *(const bf16x8*)&qg[base];
        qf1 = *(const bf16x8*)&qg[base + 32];
    }

    const int sr = tid >> 2;            // staging row 0..63
    const int sc = (tid & 3) * 8;       // staging col chunk

    // ---- sweep 1: QK^T + exp -> P_s (bf16) + rowsum ----
    float rs[4] = {0.f, 0.f, 0.f, 0.f};
    for (int t = 0; t < TT / 64; ++t) {
        __syncthreads();
        *(bf16x8*)&kv_s[sr][sc]      = *(const bf16x8*)&kpg[hb + (size_t)(t * 64 + sr) * HDIM + sc];
        *(bf16x8*)&kv_s[sr][sc + 32] = *(const bf16x8*)&kpg[hb + (size_t)(t * 64 + sr) * HDIM + sc + 32];
        __syncthreads();
        f32x4 acc = {0.f, 0.f, 0.f, 0.f};
        const bf16x8 b0 = *(const bf16x8*)&kv_s[w * 16 + lr][lg * 8];
        const bf16x8 b1 = *(const bf16x8*)&kv_s[w * 16 + lr][lg * 8 + 32];
        acc = __builtin_amdgcn_mfma_f32_16x16x32_bf16(qf0, b0, acc, 0, 0, 0);
        acc = __builtin_amdgcn_mfma_f32_16x16x32_bf16(qf1, b1, acc, 0, 0, 0);
        const int col = t * 64 + w * 16 + lr;
#pragma unroll
        for (int j = 0; j < 4; ++j) {
            const float p = __expf(acc[j]);
            P_s[lg * 4 + j][col] = f2bf(p);
            rs[j] += p;
        }
    }
    // reduce rowsums over the 16 kv-col lanes (lr)
#pragma unroll
    for (int off = 1; off < 16; off <<= 1)
#pragma unroll
        for (int j = 0; j < 4; ++j) rs[j] += __shfl_xor(rs[j], off);
    if (lr == 0) {
#pragma unroll
        for (int j = 0; j < 4; ++j) rowsum_s[w][lg * 4 + j] = rs[j];
    }
    __syncthreads();   // P_s + rowsum_s complete, visible to all waves

    // per-thread normalizers for ctx rows (reg-dim rows lg*4+j)
    float ri_c[4];
#pragma unroll
    for (int j = 0; j < 4; ++j) {
        const int r = lg * 4 + j;
        ri_c[j] = 1.f / (rowsum_s[0][r] + rowsum_s[1][r] +
                         rowsum_s[2][r] + rowsum_s[3][r]);
    }

    // ---- attn output: 16x1024 f32, barrier-free, nontemporal ----
    {
        const size_t abase = ((((size_t)b * HH + h) << 10) + q0) << 10;
#pragma unroll
        for (int it = 0; it < 8; ++it) {
            const int e = it * 2048 + tid * 8;
            const int row = e >> 10, col = e & 1023;
            const float rinv = 1.f / (rowsum_s[0][row] + rowsum_s[1][row] +
                                      rowsum_s[2][row] + rowsum_s[3][row]);
            const bf16x8 pv = *(const bf16x8*)&P_s[row][col];
            f32x4 o0, o1;
#pragma unroll
            for (int j = 0; j < 4; ++j) {
                o0[j] = bf2f((u16)pv[j]) * rinv;
                o1[j] = bf2f((u16)pv[j + 4]) * rinv;
            }
            float* dst = &attn[abase + (size_t)row * TT + col];
            __builtin_nontemporal_store(o0, (f32x4*)dst);
            __builtin_nontemporal_store(o1, (f32x4*)(dst + 4));
        }
    }

    // ---- sweep 2: PV (A = P_s rows via b128, B = kT staged) ----
    f32x4 cacc = {0.f, 0.f, 0.f, 0.f};
    for (int t = 0; t < TT / 64; ++t) {
        __syncthreads();   // all waves done with previous kv_s contents
        *(bf16x8*)&kv_s[sr][sc]      = *(const bf16x8*)&kTg[hb + (size_t)sr * TT + t * 64 + sc];
        *(bf16x8*)&kv_s[sr][sc + 32] = *(const bf16x8*)&kTg[hb + (size_t)sr * TT + t * 64 + sc + 32];
        __syncthreads();
        const bf16x8 pa0 = *(const bf16x8*)&P_s[lr][t * 64 + lg * 8];
        const bf16x8 pa1 = *(const bf16x8*)&P_s[lr][t * 64 + lg * 8 + 32];
        const bf16x8 kb0 = *(const bf16x8*)&kv_s[w * 16 + lr][lg * 8];
        const bf16x8 kb1 = *(const bf16x8*)&kv_s[w * 16 + lr][lg * 8 + 32];
        cacc = __builtin_amdgcn_mfma_f32_16x16x32_bf16(pa0, kb0, cacc, 0, 0, 0);
        cacc = __builtin_amdgcn_mfma_f32_16x16x32_bf16(pa1, kb1, cacc, 0, 0, 0);
    }

    // ctx -> bf16 [B][T][H*64]; wave w owns d-chunk w
#pragma unroll
    for (int j = 0; j < 4; ++j) {
        const int qr = q0 + lg * 4 + j;
        ch[(((size_t)b << 10) + qr) * DD + h * HDIM + w * 16 + lr] =
            f2bf(cacc[j] * ri_c[j]);
    }
}

extern "C" void kernel_launch(void* const* d_in, const int* in_sizes, int n_in,
                              void* d_out, int out_size, void* d_ws, size_t ws_size,
                              hipStream_t stream)
{
    const float* x  = (const float*)d_in[0];
    const float* pe = (const float*)d_in[1];
    const float* Wc = (const float*)d_in[2];
    const float* bc = (const float*)d_in[3];
    const float* Wp = (const float*)d_in[4];
    const float* bp = (const float*)d_in[5];
    const float* Wo = (const float*)d_in[6];
    const float* bo = (const float*)d_in[7];

    float* out  = (float*)d_out;                         // [B][T][D]
    float* attn = out + (size_t)MM * DD;                 // [B][H][T][T]

    // 64 MB workspace layout (in-order stream => safe region reuse)
    char* ws = (char*)d_ws;
    float* kf32 = (float*)(ws);                          // [0,16M)   k fp32
    u16* q16  = (u16*)(ws + ((size_t)16 << 20));         // [16,24M)
    u16* k16  = (u16*)(ws + ((size_t)24 << 20));         // [24,32M)
    u16* kp16 = (u16*)(ws + ((size_t)32 << 20));         // [32,40M)
    u16* k16T = (u16*)(ws + ((size_t)56 << 20));         // [56,64M)  k transposed
    u16* xh  = (u16*)(ws + ((size_t)40 << 20));          // 8MB
    u16* xl  = (u16*)(ws + ((size_t)48 << 20));          // 8MB
    u16* Wch = (u16*)(ws + ((size_t)56 << 20));          // 4MB (k16T area, dead before ktrans)
    u16* Wcl = (u16*)(ws + ((size_t)60 << 20));          // 4MB
    u16* peh = xh, *pel = xl;                            // after cqk
    u16* Wph = (u16*)(ws + ((size_t)24 << 20));          // k16 area, dead after ktrans
    u16* Wpl = (u16*)(ws + ((size_t)26 << 20));
    u16* chh = xh;                                       // ctx bf16, after pk
    u16* Woh = (u16*)(ws + ((size_t)48 << 20));          // 2MB (xl dead)

    // 1) splits for cqk
    split_kernel<<<4096, 256, 0, stream>>>(x, xh, xl);
    split_kernel<<<2048, 256, 0, stream>>>(Wc, Wch, Wcl);
    // 2) cqk = x @ Wc^T + bc -> q16 (scaled), kf32, k16
    gemm_mfma<true, 0><<<dim3(16, 32), 256, 0, stream>>>(
        xh, xl, Wch, Wcl, bc, kf32, q16, k16, nullptr, MM, 2048, DD);
    // 3) k16T = transpose(k16)  (overwrites Wc split -- dead after gemm)
    ktrans_kernel<<<dim3(16, HH, BB), 256, 0, stream>>>(k16, k16T);
    // 4) splits for pk (Wp split into k16's region -- k16 dead after ktrans)
    split_kernel<<<4096, 256, 0, stream>>>(pe, peh, pel);
    split_kernel<<<1024, 256, 0, stream>>>(Wp, Wph, Wpl);
    // 5) pk = pe @ Wp^T + bp; kp16 = bf16(pk + k)
    gemm_mfma<true, 1><<<dim3(8, 32), 256, 0, stream>>>(
        peh, pel, Wph, Wpl, bp, nullptr, kp16, nullptr, kf32, MM, 1024, DD);
    // 6) attention: attn f32 + ctx bf16
    attn_fused<<<dim3(TT / 16, HH, BB), 256, 0, stream>>>(
        q16, k16T, kp16, attn, chh);
    // 7) split Wo (hi only), out = ctx @ Wo^T + bo
    split_kernel<<<1024, 256, 0, stream>>>(Wo, Woh, nullptr);
    gemm_mfma<false, 2><<<dim3(8, 32), 256, 0, stream>>>(
        chh, nullptr, Woh, nullptr, bo, out, nullptr, nullptr, nullptr, MM, 1024, DD);
}